// Round 1
// baseline (12621.478 us; speedup 1.0000x reference)
//
#include <hip/hip_runtime.h>

#define T_STEPS 256
#define BATCH   64
#define DIN     512
#define HID     1024
#define KTOT    1536
#define NBLK    256          // persistent blocks, 1 per CU
#define NPB     16           // packed W rows (gate-dims) per block
#define HPB     4            // hidden units per block (NPB/4)
#define WPITCH  1544         // 1536 + 8 ushort pad (breaks LDS bank alignment)

typedef __attribute__((ext_vector_type(8))) short short8;
typedef __attribute__((ext_vector_type(4))) float f32x4;

// ---- workspace layout (bytes) ----
#define WS_WPACK 0                       // 4096*1544*2      = 12,648,448
#define WS_XBF   12648448                // 256*64*512*2     = 16,777,216
#define WS_HBF   29425664                // 2*64*1024*2      =    262,144
#define WS_BPK   29687808                // 4096*4           =     16,384
#define WS_SLOTS 29704192                // 256*4            =      1,024

__device__ inline unsigned short f2bf(float x) {
  unsigned u = __builtin_bit_cast(unsigned, x);
  u += 0x7FFF + ((u >> 16) & 1);        // round-to-nearest-even
  return (unsigned short)(u >> 16);
}

// pack inputs -> bf16, zero h0 buffers, zero barrier slots, pack biases
__global__ void prep_x(const float* __restrict__ x, ushort* __restrict__ Xbf,
                       ushort* __restrict__ hbf, unsigned* __restrict__ slots,
                       const float* __restrict__ bfv, const float* __restrict__ biv,
                       const float* __restrict__ bgv, const float* __restrict__ bov,
                       float* __restrict__ bpack) {
  unsigned i = blockIdx.x * 256 + threadIdx.x;          // 0 .. 2,097,151 (T*B*D/4)
  float4 v = ((const float4*)x)[i];
  ushort4 o = make_ushort4(f2bf(v.x), f2bf(v.y), f2bf(v.z), f2bf(v.w));
  ((ushort4*)Xbf)[i] = o;
  if (i < (2 * BATCH * HID) / 4) ((ushort4*)hbf)[i] = make_ushort4(0, 0, 0, 0);
  if (i < 4096) {
    int bl = i >> 4, n = i & 15, gate = n >> 2, jj = n & 3;
    int j = bl * HPB + jj;
    const float* b = (gate == 0) ? bfv : (gate == 1) ? biv : (gate == 2) ? bgv : bov;
    bpack[i] = b[j];
  }
  if (i < NBLK) slots[i] = 0;
}

// pack weights fp32 -> bf16, block-tailored row order, padded pitch
__global__ void prep_w(const float* __restrict__ Wf, const float* __restrict__ Wi,
                       const float* __restrict__ Wg, const float* __restrict__ Wo,
                       ushort* __restrict__ Wpack) {
  int row = blockIdx.x;                                  // 0..4095 packed row
  int bl = row >> 4, n = row & 15, gate = n >> 2, jj = n & 3;
  int j = bl * HPB + jj;
  const float* src = ((gate == 0) ? Wf : (gate == 1) ? Wi : (gate == 2) ? Wg : Wo)
                     + (size_t)j * KTOT;
  ushort* dst = Wpack + (size_t)row * WPITCH;
  for (int idx = threadIdx.x; idx < KTOT / 4; idx += 256) {
    float4 v = ((const float4*)src)[idx];
    ((ushort4*)dst)[idx] = make_ushort4(f2bf(v.x), f2bf(v.y), f2bf(v.z), f2bf(v.w));
  }
}

__launch_bounds__(256)
__global__ void lstm_persist(const ushort* __restrict__ Wpack,
                             const ushort* __restrict__ Xbf,
                             ushort* __restrict__ hbf,
                             const float* __restrict__ bpack,
                             unsigned* __restrict__ slots,
                             float* __restrict__ out) {
  __shared__ __align__(16) ushort Wlds[NPB * WPITCH];    // 49,408 B
  __shared__ float gates[NPB][BATCH + 4];                // [n][m], pad -> 2-way max
  __shared__ float blds[NPB];
  __shared__ float clds[HPB][BATCH + 1];                 // fp32 cell state

  const int tid  = threadIdx.x;
  const int bl   = blockIdx.x;
  const int lane = tid & 63;
  const int wave = tid >> 6;

  { // W slice -> LDS (once, reused all 256 steps)
    const uint4* src = (const uint4*)(Wpack + (size_t)bl * NPB * WPITCH);
    uint4* dst = (uint4*)Wlds;
    for (int i = tid; i < NPB * WPITCH / 8; i += 256) dst[i] = src[i];
  }
  if (tid < NPB) blds[tid] = bpack[bl * NPB + tid];
  for (int i = tid; i < HPB * (BATCH + 1); i += 256) (&clds[0][0])[i] = 0.f;
  __syncthreads();

  // MFMA 16x16x32 bf16: A[m=lane&15][k=(lane>>4)*8+j], B[n=lane&15][k same],
  // D: n=lane&15, m=(lane>>4)*4+reg
  const int m0    = wave * 16 + (lane & 15);
  const int kgrp8 = (lane >> 4) * 8;
  const ushort* wrow = Wlds + (lane & 15) * WPITCH + kgrp8;

  const f32x4 vzero = {0.f, 0.f, 0.f, 0.f};
  f32x4 acc0 = vzero, acc1 = vzero;                      // 2 k-parity chains

  auto xpart = [&](int t) {                              // k = 0..511 (no h dep)
    acc0 = vzero; acc1 = vzero;
    const ushort* xp = Xbf + ((size_t)t * BATCH + m0) * DIN + kgrp8;
#pragma unroll
    for (int ki = 0; ki < 16; ki += 2) {
      short8 b0 = *(const short8*)(wrow + ki * 32);
      short8 a0 = *(const short8*)(xp + ki * 32);
      short8 b1 = *(const short8*)(wrow + (ki + 1) * 32);
      short8 a1 = *(const short8*)(xp + (ki + 1) * 32);
      acc0 = __builtin_amdgcn_mfma_f32_16x16x32_bf16(a0, b0, acc0, 0, 0, 0);
      acc1 = __builtin_amdgcn_mfma_f32_16x16x32_bf16(a1, b1, acc1, 0, 0, 0);
    }
  };
  auto hpart = [&](int p) {                              // k = 512..1535
    const ushort* hp = hbf + (size_t)p * (BATCH * HID) + (size_t)m0 * HID + kgrp8;
    const ushort* wr = wrow + DIN;
#pragma unroll 8
    for (int ki = 0; ki < 32; ki += 2) {
      short8 b0 = *(const short8*)(wr + ki * 32);
      short8 a0 = *(const short8*)(hp + ki * 32);
      short8 b1 = *(const short8*)(wr + (ki + 1) * 32);
      short8 a1 = *(const short8*)(hp + (ki + 1) * 32);
      acc0 = __builtin_amdgcn_mfma_f32_16x16x32_bf16(a0, b0, acc0, 0, 0, 0);
      acc1 = __builtin_amdgcn_mfma_f32_16x16x32_bf16(a1, b1, acc1, 0, 0, 0);
    }
  };

  xpart(0);
  for (int t = 0; t < T_STEPS; ++t) {
    // ---- wait until every block published h_t (slots[b] >= t) ----
    if (tid < 64) {
      const unsigned tu = (unsigned)t;
      for (;;) {
        unsigned v0 = __hip_atomic_load(&slots[lane],       __ATOMIC_RELAXED, __HIP_MEMORY_SCOPE_AGENT);
        unsigned v1 = __hip_atomic_load(&slots[lane + 64],  __ATOMIC_RELAXED, __HIP_MEMORY_SCOPE_AGENT);
        unsigned v2 = __hip_atomic_load(&slots[lane + 128], __ATOMIC_RELAXED, __HIP_MEMORY_SCOPE_AGENT);
        unsigned v3 = __hip_atomic_load(&slots[lane + 192], __ATOMIC_RELAXED, __HIP_MEMORY_SCOPE_AGENT);
        if (__all((v0 >= tu) && (v1 >= tu) && (v2 >= tu) && (v3 >= tu))) break;
        __builtin_amdgcn_s_sleep(1);
      }
    }
    __syncthreads();
    __threadfence();                                     // acquire: invalidate stale h lines

    hpart(t & 1);

    { // store gate tile [n][m] to LDS
      f32x4 acc = acc0 + acc1;
      int n0 = lane & 15;
      int mq = wave * 16 + (lane >> 4) * 4;
      *(f32x4*)&gates[n0][mq] = acc;
    }
    __syncthreads();

    { // elementwise LSTM cell: one (m, jj) per thread
      int jj = tid & 3, m = tid >> 2;
      float fp = gates[jj][m]      + blds[jj];
      float ip = gates[4 + jj][m]  + blds[4 + jj];
      float gp = gates[8 + jj][m]  + blds[8 + jj];
      float op = gates[12 + jj][m] + blds[12 + jj];
      float fs = 1.f / (1.f + __expf(-fp));
      float is = 1.f / (1.f + __expf(-ip));
      float os = 1.f / (1.f + __expf(-op));
      float gt = 1.f - 2.f / (__expf(2.f * gp) + 1.f);   // tanh, inf-safe
      float c  = fs * clds[jj][m] + is * gt;
      clds[jj][m] = c;
      float th = 1.f - 2.f / (__expf(2.f * c) + 1.f);
      float h  = os * th;
      int jg = bl * HPB + jj;
      out[(size_t)t * (BATCH * HID) + (size_t)m * HID + jg] = h;
      hbf[(size_t)((t + 1) & 1) * (BATCH * HID) + (size_t)m * HID + jg] = f2bf(h);
      if (t == T_STEPS - 1) {
        out[(size_t)T_STEPS * BATCH * HID + (size_t)m * HID + jg] = h;                 // hT
        out[(size_t)T_STEPS * BATCH * HID + BATCH * HID + (size_t)m * HID + jg] = c;   // cT
      }
    }

    if (t < T_STEPS - 1) {
      __threadfence();                                   // publish h_{t+1}
      __syncthreads();
      if (tid == 0)
        __hip_atomic_store(&slots[bl], (unsigned)(t + 1), __ATOMIC_RELEASE, __HIP_MEMORY_SCOPE_AGENT);
      xpart(t + 1);                                      // hide barrier latency
    }
  }
}

extern "C" void kernel_launch(void* const* d_in, const int* in_sizes, int n_in,
                              void* d_out, int out_size, void* d_ws, size_t ws_size,
                              hipStream_t stream) {
  const float* x   = (const float*)d_in[0];
  const float* Wf  = (const float*)d_in[1];
  const float* bfv = (const float*)d_in[2];
  const float* Wi  = (const float*)d_in[3];
  const float* biv = (const float*)d_in[4];
  const float* Wg  = (const float*)d_in[5];
  const float* bgv = (const float*)d_in[6];
  const float* Wo  = (const float*)d_in[7];
  const float* bov = (const float*)d_in[8];

  char* ws = (char*)d_ws;
  ushort*   Wpack = (ushort*)(ws + WS_WPACK);
  ushort*   Xbf   = (ushort*)(ws + WS_XBF);
  ushort*   hbf   = (ushort*)(ws + WS_HBF);
  float*    bpack = (float*)(ws + WS_BPK);
  unsigned* slots = (unsigned*)(ws + WS_SLOTS);
  float*    out   = (float*)d_out;

  prep_x<<<dim3((T_STEPS * BATCH * DIN) / 4 / 256), dim3(256), 0, stream>>>(
      x, Xbf, hbf, slots, bfv, biv, bgv, bov, bpack);
  prep_w<<<dim3(4096), dim3(256), 0, stream>>>(Wf, Wi, Wg, Wo, Wpack);

  const ushort* Wpc = Wpack;
  const ushort* Xbc = Xbf;
  const float*  bpc = bpack;
  void* args[] = {(void*)&Wpc, (void*)&Xbc, (void*)&hbf,
                  (void*)&bpc, (void*)&slots, (void*)&out};
  hipLaunchCooperativeKernel((const void*)lstm_persist, dim3(NBLK), dim3(256),
                             args, 0, stream);
}

// Round 2
// 2750.117 us; speedup vs baseline: 4.5894x; 4.5894x over previous
//
#include <hip/hip_runtime.h>

#define T_STEPS 256
#define BATCH   64
#define DIN     512
#define HID     1024
#define KTOT    1536
#define NBLK    256          // persistent blocks, 1 per CU
#define NPB     16           // packed W rows (gate-dims) per block
#define WPITCH  1544         // 1536 + 8 ushort pad (breaks LDS bank alignment)

// block bl owns output columns [OWNER(bl)*4, OWNER(bl)*4+4). Swizzled so the
// 8 column-groups sharing a 128B out-line all live on one XCD (bl%8 = XCD).
#define OWNER(bl) ((((bl) & 7) << 5) | ((bl) >> 3))

typedef __attribute__((ext_vector_type(8))) short short8;
typedef __attribute__((ext_vector_type(4))) float f32x4;
typedef __attribute__((ext_vector_type(2))) unsigned long long ull2;

// ---- workspace layout (bytes) ----
#define WS_WPACK 0                       // 4096*1544*2      = 12,648,448
#define WS_XBF   12648448                // 256*64*512*2     = 16,777,216
#define WS_HBF   29425664                // 2*64*1024*2      =    262,144
#define WS_BPK   29687808                // 4096*4           =     16,384
#define WS_SLOTS 29704192                // 256*4            =      1,024

__device__ inline unsigned short f2bf(float x) {
  unsigned u = __builtin_bit_cast(unsigned, x);
  u += 0x7FFF + ((u >> 16) & 1);        // round-to-nearest-even
  return (unsigned short)(u >> 16);
}

// pack inputs -> bf16, zero h0 buffers, zero barrier slots, pack biases
__global__ void prep_x(const float* __restrict__ x, ushort* __restrict__ Xbf,
                       ushort* __restrict__ hbf, unsigned* __restrict__ slots,
                       const float* __restrict__ bfv, const float* __restrict__ biv,
                       const float* __restrict__ bgv, const float* __restrict__ bov,
                       float* __restrict__ bpack) {
  unsigned i = blockIdx.x * 256 + threadIdx.x;          // 0 .. 2,097,151 (T*B*D/4)
  float4 v = ((const float4*)x)[i];
  ushort4 o = make_ushort4(f2bf(v.x), f2bf(v.y), f2bf(v.z), f2bf(v.w));
  ((ushort4*)Xbf)[i] = o;
  if (i < (2 * BATCH * HID) / 4) ((ushort4*)hbf)[i] = make_ushort4(0, 0, 0, 0);
  if (i < 4096) {
    int bl = i >> 4, n = i & 15, gate = n >> 2, jj = n & 3;
    int j = OWNER(bl) * 4 + jj;
    const float* b = (gate == 0) ? bfv : (gate == 1) ? biv : (gate == 2) ? bgv : bov;
    bpack[i] = b[j];
  }
  if (i < NBLK) slots[i] = 0;
}

// pack weights fp32 -> bf16, block-tailored row order, padded pitch
__global__ void prep_w(const float* __restrict__ Wf, const float* __restrict__ Wi,
                       const float* __restrict__ Wg, const float* __restrict__ Wo,
                       ushort* __restrict__ Wpack) {
  int row = blockIdx.x;                                  // 0..4095 packed row
  int bl = row >> 4, n = row & 15, gate = n >> 2, jj = n & 3;
  int j = OWNER(bl) * 4 + jj;
  const float* src = ((gate == 0) ? Wf : (gate == 1) ? Wi : (gate == 2) ? Wg : Wo)
                     + (size_t)j * KTOT;
  ushort* dst = Wpack + (size_t)row * WPITCH;
  for (int idx = threadIdx.x; idx < KTOT / 4; idx += 256) {
    float4 v = ((const float4*)src)[idx];
    ((ushort4*)dst)[idx] = make_ushort4(f2bf(v.x), f2bf(v.y), f2bf(v.z), f2bf(v.w));
  }
}

__launch_bounds__(256)
__global__ void lstm_persist(const ushort* __restrict__ Wpack,
                             const ushort* __restrict__ Xbf,
                             unsigned long long* __restrict__ hbf64,
                             const float* __restrict__ bpack,
                             unsigned* __restrict__ slots,
                             float* __restrict__ out) {
  __shared__ __align__(16) ushort Wlds[NPB * WPITCH];    // 49,408 B
  __shared__ float gates[NPB][BATCH + 4];                // [n][m]
  __shared__ float blds[NPB];
  __shared__ float clds[4][BATCH + 1];                   // fp32 cell state [jj][m]

  const int tid  = threadIdx.x;
  const int bl   = blockIdx.x;
  const int lane = tid & 63;
  const int wave = tid >> 6;
  const int jbase = OWNER(bl) * 4;                       // owned out/h columns

  { // W slice -> LDS (once, reused all 256 steps)
    const uint4* src = (const uint4*)(Wpack + (size_t)bl * NPB * WPITCH);
    uint4* dst = (uint4*)Wlds;
    for (int i = tid; i < NPB * WPITCH / 8; i += 256) dst[i] = src[i];
  }
  if (tid < NPB) blds[tid] = bpack[bl * NPB + tid];
  for (int i = tid; i < 4 * (BATCH + 1); i += 256) (&clds[0][0])[i] = 0.f;
  __syncthreads();

  // MFMA 16x16x32 bf16: A[m=lane&15][k=(lane>>4)*8+j], B[n=lane&15][k same],
  // D: n=lane&15, m=(lane>>4)*4+reg
  const int m0    = wave * 16 + (lane & 15);
  const int kgrp8 = (lane >> 4) * 8;
  const ushort* wrow = Wlds + (lane & 15) * WPITCH + kgrp8;

  const f32x4 vzero = {0.f, 0.f, 0.f, 0.f};
  f32x4 acc0 = vzero, acc1 = vzero;

  auto xpart = [&](int t) {                              // k = 0..511 (no h dep)
    acc0 = vzero; acc1 = vzero;
    const ushort* xp = Xbf + ((size_t)t * BATCH + m0) * DIN + kgrp8;
#pragma unroll
    for (int ki = 0; ki < 16; ki += 2) {
      short8 b0 = *(const short8*)(wrow + ki * 32);
      short8 a0 = *(const short8*)(xp + ki * 32);
      short8 b1 = *(const short8*)(wrow + (ki + 1) * 32);
      short8 a1 = *(const short8*)(xp + (ki + 1) * 32);
      acc0 = __builtin_amdgcn_mfma_f32_16x16x32_bf16(a0, b0, acc0, 0, 0, 0);
      acc1 = __builtin_amdgcn_mfma_f32_16x16x32_bf16(a1, b1, acc1, 0, 0, 0);
    }
  };
  // h-part: A-frags loaded as agent-scope relaxed atomics (sc0 sc1 -> L3
  // coherent, bypass L2) so NO cache-maintenance fence is ever needed.
  auto hpart = [&](int p) {                              // k = 512..1535
    const unsigned long long* hp =
        hbf64 + ((size_t)p * (BATCH * HID) + (size_t)m0 * HID + kgrp8) / 4;
    const ushort* wr = wrow + DIN;
#pragma unroll 8
    for (int ki = 0; ki < 32; ki += 2) {
      ull2 a0v, a1v;
      a0v.x = __hip_atomic_load(hp + ki * 8,     __ATOMIC_RELAXED, __HIP_MEMORY_SCOPE_AGENT);
      a0v.y = __hip_atomic_load(hp + ki * 8 + 1, __ATOMIC_RELAXED, __HIP_MEMORY_SCOPE_AGENT);
      a1v.x = __hip_atomic_load(hp + ki * 8 + 8, __ATOMIC_RELAXED, __HIP_MEMORY_SCOPE_AGENT);
      a1v.y = __hip_atomic_load(hp + ki * 8 + 9, __ATOMIC_RELAXED, __HIP_MEMORY_SCOPE_AGENT);
      short8 b0 = *(const short8*)(wr + ki * 32);
      short8 b1 = *(const short8*)(wr + (ki + 1) * 32);
      acc0 = __builtin_amdgcn_mfma_f32_16x16x32_bf16(
                 __builtin_bit_cast(short8, a0v), b0, acc0, 0, 0, 0);
      acc1 = __builtin_amdgcn_mfma_f32_16x16x32_bf16(
                 __builtin_bit_cast(short8, a1v), b1, acc1, 0, 0, 0);
    }
  };

  xpart(0);
  for (int t = 0; t < T_STEPS; ++t) {
    // ---- wait until every block published h_t (slots[b] >= t) ----
    if (tid < 64) {
      const unsigned tu = (unsigned)t;
      for (;;) {
        unsigned v0 = __hip_atomic_load(&slots[lane],       __ATOMIC_RELAXED, __HIP_MEMORY_SCOPE_AGENT);
        unsigned v1 = __hip_atomic_load(&slots[lane + 64],  __ATOMIC_RELAXED, __HIP_MEMORY_SCOPE_AGENT);
        unsigned v2 = __hip_atomic_load(&slots[lane + 128], __ATOMIC_RELAXED, __HIP_MEMORY_SCOPE_AGENT);
        unsigned v3 = __hip_atomic_load(&slots[lane + 192], __ATOMIC_RELAXED, __HIP_MEMORY_SCOPE_AGENT);
        if (__all((v0 >= tu) && (v1 >= tu) && (v2 >= tu) && (v3 >= tu))) break;
        __builtin_amdgcn_s_sleep(1);
      }
    }
    __syncthreads();            // h_t visible (sc1 reads need no invalidate)

    hpart(t & 1);

    { // store gate tile [n][m] to LDS
      f32x4 acc = acc0 + acc1;
      int n0 = lane & 15;
      int mq = wave * 16 + (lane >> 4) * 4;
      *(f32x4*)&gates[n0][mq] = acc;
    }
    __syncthreads();

    if (tid < BATCH) {          // wave 0: elementwise cell, one batch row each
      const int m = tid;
      float h4[4], c4[4];
#pragma unroll
      for (int jj = 0; jj < 4; ++jj) {
        float fp = gates[jj][m]      + blds[jj];
        float ip = gates[4 + jj][m]  + blds[4 + jj];
        float gp = gates[8 + jj][m]  + blds[8 + jj];
        float op = gates[12 + jj][m] + blds[12 + jj];
        float fs = 1.f / (1.f + __expf(-fp));
        float is = 1.f / (1.f + __expf(-ip));
        float os = 1.f / (1.f + __expf(-op));
        float gt = 1.f - 2.f / (__expf(2.f * gp) + 1.f);   // tanh, inf-safe
        float c  = fs * clds[jj][m] + is * gt;
        clds[jj][m] = c;
        float th = 1.f - 2.f / (__expf(2.f * c) + 1.f);
        h4[jj] = os * th;
        c4[jj] = c;
      }
      // publish h_{t+1}: one packed u64 agent-atomic store (sc0 sc1 -> L3)
      unsigned long long hp = (unsigned long long)f2bf(h4[0])
                            | ((unsigned long long)f2bf(h4[1]) << 16)
                            | ((unsigned long long)f2bf(h4[2]) << 32)
                            | ((unsigned long long)f2bf(h4[3]) << 48);
      __hip_atomic_store(hbf64 + (size_t)((t + 1) & 1) * (BATCH * HID / 4)
                               + (size_t)m * (HID / 4) + (jbase >> 2),
                         hp, __ATOMIC_RELAXED, __HIP_MEMORY_SCOPE_AGENT);
      __asm__ volatile("" ::: "memory");
      __builtin_amdgcn_s_waitcnt(0);   // drain own h-store to L3
      __asm__ volatile("" ::: "memory");
      if (tid == 0)
        __hip_atomic_store(&slots[bl], (unsigned)(t + 1),
                           __ATOMIC_RELAXED, __HIP_MEMORY_SCOPE_AGENT);
      // out stores: normal cached writes, off the critical path, full-line
      // merge in this XCD's L2 thanks to the OWNER swizzle
      float4 ov = make_float4(h4[0], h4[1], h4[2], h4[3]);
      *(float4*)(out + (size_t)t * (BATCH * HID) + (size_t)m * HID + jbase) = ov;
      if (t == T_STEPS - 1) {
        *(float4*)(out + (size_t)T_STEPS * BATCH * HID + (size_t)m * HID + jbase) = ov;
        *(float4*)(out + (size_t)T_STEPS * BATCH * HID + BATCH * HID
                       + (size_t)m * HID + jbase) = make_float4(c4[0], c4[1], c4[2], c4[3]);
      }
    }

    if (t < T_STEPS - 1) xpart(t + 1);   // waves 1-3 start immediately
  }
}

extern "C" void kernel_launch(void* const* d_in, const int* in_sizes, int n_in,
                              void* d_out, int out_size, void* d_ws, size_t ws_size,
                              hipStream_t stream) {
  const float* x   = (const float*)d_in[0];
  const float* Wf  = (const float*)d_in[1];
  const float* bfv = (const float*)d_in[2];
  const float* Wi  = (const float*)d_in[3];
  const float* biv = (const float*)d_in[4];
  const float* Wg  = (const float*)d_in[5];
  const float* bgv = (const float*)d_in[6];
  const float* Wo  = (const float*)d_in[7];
  const float* bov = (const float*)d_in[8];

  char* ws = (char*)d_ws;
  ushort*             Wpack = (ushort*)(ws + WS_WPACK);
  ushort*             Xbf   = (ushort*)(ws + WS_XBF);
  unsigned long long* hbf64 = (unsigned long long*)(ws + WS_HBF);
  float*              bpack = (float*)(ws + WS_BPK);
  unsigned*           slots = (unsigned*)(ws + WS_SLOTS);
  float*              out   = (float*)d_out;

  prep_x<<<dim3((T_STEPS * BATCH * DIN) / 4 / 256), dim3(256), 0, stream>>>(
      x, Xbf, (ushort*)hbf64, slots, bfv, biv, bgv, bov, bpack);
  prep_w<<<dim3(4096), dim3(256), 0, stream>>>(Wf, Wi, Wg, Wo, Wpack);

  const ushort* Wpc = Wpack;
  const ushort* Xbc = Xbf;
  const float*  bpc = bpack;
  void* args[] = {(void*)&Wpc, (void*)&Xbc, (void*)&hbf64,
                  (void*)&bpc, (void*)&slots, (void*)&out};
  hipLaunchCooperativeKernel((const void*)lstm_persist, dim3(NBLK), dim3(256),
                             args, 0, stream);
}

// Round 4
// 2145.049 us; speedup vs baseline: 5.8840x; 1.2821x over previous
//
#include <hip/hip_runtime.h>

#define T_STEPS 256
#define BATCH   64
#define DIN     512
#define HID     1024
#define KTOT    1536
#define NBLK    128          // persistent blocks, 1 per CU (halves h broadcast)
#define NPB     32           // packed W rows (gate-dims) per block -> 8 hidden cols
#define WPITCH  1544         // 1536 + 8 ushort pad (LDS bank decorrelation)

// block bl owns hidden cols [OWNER(bl)*8, +8). Swizzle: the 4 col-groups in one
// 128B out-line share an XCD (bl%8 = XCD heuristic; perf-only, not correctness).
#define OWNER(bl) ((((bl) & 7) << 4) | ((bl) >> 3))

typedef __attribute__((ext_vector_type(8))) short short8;
typedef __attribute__((ext_vector_type(4))) float f32x4;
typedef __attribute__((ext_vector_type(4))) int   i32x4;

// ---- workspace layout (bytes) ----
#define WS_WPACK 0                       // 4096*1544*2      = 12,648,448
#define WS_XBF   12648448                // 256*64*512*2     = 16,777,216
#define WS_HBF   29425664                // 2*64*1024*2      =    262,144
#define WS_BPK   29687808                // 4096*4           =     16,384
#define WS_SLOTS 29704192                // 128*4

#define MFMA(acc, a, b) acc = __builtin_amdgcn_mfma_f32_16x16x32_bf16(a, b, acc, 0, 0, 0)

// uncached (L3-coherent, bypass L1/L2) 16B load; OFF = byte literal
#define GLD(D, P, OFF) \
  asm volatile("global_load_dwordx4 %0, %1, off offset:" #OFF " sc0 sc1" \
               : "=v"(D) : "v"(P))
// wait until only N vmem ops outstanding; ties the 8 batch regs (named vars,
// NOT array elements -- tied indirect inputs don't compile)
#define TIE(N, x0, x1, x2, x3, x4, x5, x6, x7) \
  asm volatile("s_waitcnt vmcnt(" #N ")" \
               : "+v"(x0), "+v"(x1), "+v"(x2), "+v"(x3), \
                 "+v"(x4), "+v"(x5), "+v"(x6), "+v"(x7))

__device__ inline unsigned short f2bf(float x) {
  unsigned u = __builtin_bit_cast(unsigned, x);
  u += 0x7FFF + ((u >> 16) & 1);        // round-to-nearest-even
  return (unsigned short)(u >> 16);
}

// pack inputs -> bf16, zero h buffers, zero barrier slots, pack biases
__global__ void prep_x(const float* __restrict__ x, ushort* __restrict__ Xbf,
                       ushort* __restrict__ hbf, unsigned* __restrict__ slots,
                       const float* __restrict__ bfv, const float* __restrict__ biv,
                       const float* __restrict__ bgv, const float* __restrict__ bov,
                       float* __restrict__ bpack) {
  unsigned i = blockIdx.x * 256 + threadIdx.x;          // 0 .. 2,097,151
  float4 v = ((const float4*)x)[i];
  ushort4 o = make_ushort4(f2bf(v.x), f2bf(v.y), f2bf(v.z), f2bf(v.w));
  ((ushort4*)Xbf)[i] = o;
  if (i < (2 * BATCH * HID) / 4) ((ushort4*)hbf)[i] = make_ushort4(0, 0, 0, 0);
  if (i < NBLK * NPB) {
    int bl = i >> 5, n = i & 31, gate = n >> 3, jj = n & 7;
    int j = OWNER(bl) * 8 + jj;
    const float* b = (gate == 0) ? bfv : (gate == 1) ? biv : (gate == 2) ? bgv : bov;
    bpack[i] = b[j];
  }
  if (i < NBLK) slots[i] = 0;
}

// pack weights fp32 -> bf16, block-tailored row order, padded pitch
__global__ void prep_w(const float* __restrict__ Wf, const float* __restrict__ Wi,
                       const float* __restrict__ Wg, const float* __restrict__ Wo,
                       ushort* __restrict__ Wpack) {
  int row = blockIdx.x;                                  // 0..4095 packed row
  int bl = row >> 5, n = row & 31, gate = n >> 3, jj = n & 7;
  int j = OWNER(bl) * 8 + jj;
  const float* src = ((gate == 0) ? Wf : (gate == 1) ? Wi : (gate == 2) ? Wg : Wo)
                     + (size_t)j * KTOT;
  ushort* dst = Wpack + (size_t)row * WPITCH;
  for (int idx = threadIdx.x; idx < KTOT / 4; idx += 256) {
    float4 v = ((const float4*)src)[idx];
    ((ushort4*)dst)[idx] = make_ushort4(f2bf(v.x), f2bf(v.y), f2bf(v.z), f2bf(v.w));
  }
}

__launch_bounds__(256)
__global__ void lstm_persist(const ushort* __restrict__ Wpack,
                             const ushort* __restrict__ Xbf,
                             ushort* __restrict__ hbf,
                             const float* __restrict__ bpack,
                             unsigned* __restrict__ slots,
                             float* __restrict__ out) {
  __shared__ __align__(16) ushort Wlds[NPB * WPITCH];    // 98,816 B
  __shared__ float gates[NPB][BATCH + 4];                // [n][m] 8,704 B
  __shared__ float blds[NPB];
  __shared__ float clds[8][BATCH + 1];                   // fp32 cell state [jj][m]

  const int tid  = threadIdx.x;
  const int bl   = blockIdx.x;
  const int lane = tid & 63;
  const int wave = tid >> 6;
  const int jbase = OWNER(bl) * 8;                       // owned out/h columns

  { // W slice -> LDS (once, reused all 256 steps)
    const uint4* src = (const uint4*)(Wpack + (size_t)bl * NPB * WPITCH);
    uint4* dst = (uint4*)Wlds;
    for (int i = tid; i < NPB * WPITCH / 8; i += 256) dst[i] = src[i];
  }
  if (tid < NPB) blds[tid] = bpack[bl * NPB + tid];
  for (int i = tid; i < 8 * (BATCH + 1); i += 256) (&clds[0][0])[i] = 0.f;
  __syncthreads();

  // MFMA 16x16x32 bf16: A[m=lane&15][k=(lane>>4)*8+j], B[n=lane&15][k same],
  // D: n=lane&15, m=(lane>>4)*4+reg
  const int m0    = wave * 16 + (lane & 15);
  const int kgrp8 = (lane >> 4) * 8;
  const ushort* wx0 = Wlds + (lane & 15) * WPITCH + kgrp8;          // tile0, x-K
  const ushort* wx1 = wx0 + 16 * WPITCH;                            // tile1, x-K
  const ushort* wh0 = wx0 + DIN;                                    // tile0, h-K
  const ushort* wh1 = wx1 + DIN;                                    // tile1, h-K

  const f32x4 vzero = {0.f, 0.f, 0.f, 0.f};
  f32x4 acc00 = vzero, acc01 = vzero, acc10 = vzero, acc11 = vzero;

  auto xpart = [&](int t) {                              // k = 0..511 (no h dep)
    acc00 = vzero; acc01 = vzero; acc10 = vzero; acc11 = vzero;
    const ushort* xp = Xbf + ((size_t)t * BATCH + m0) * DIN + kgrp8;
#pragma unroll
    for (int ki = 0; ki < 16; ++ki) {
      short8 a  = *(const short8*)(xp + ki * 32);
      short8 b0 = *(const short8*)(wx0 + ki * 32);
      short8 b1 = *(const short8*)(wx1 + ki * 32);
      if (ki & 1) { MFMA(acc01, a, b0); MFMA(acc11, a, b1); }
      else        { MFMA(acc00, a, b0); MFMA(acc10, a, b1); }
    }
  };
  // consume 8 A-frags (by value, already tied through the waitcnt)
  auto consume8 = [&](i32x4 v0, i32x4 v1, i32x4 v2, i32x4 v3,
                      i32x4 v4, i32x4 v5, i32x4 v6, i32x4 v7, int kiBase) {
    const ushort* b0p = wh0 + kiBase * 32;
    const ushort* b1p = wh1 + kiBase * 32;
    MFMA(acc00, __builtin_bit_cast(short8, v0), *(const short8*)(b0p + 0 * 32));
    MFMA(acc10, __builtin_bit_cast(short8, v0), *(const short8*)(b1p + 0 * 32));
    MFMA(acc01, __builtin_bit_cast(short8, v1), *(const short8*)(b0p + 1 * 32));
    MFMA(acc11, __builtin_bit_cast(short8, v1), *(const short8*)(b1p + 1 * 32));
    MFMA(acc00, __builtin_bit_cast(short8, v2), *(const short8*)(b0p + 2 * 32));
    MFMA(acc10, __builtin_bit_cast(short8, v2), *(const short8*)(b1p + 2 * 32));
    MFMA(acc01, __builtin_bit_cast(short8, v3), *(const short8*)(b0p + 3 * 32));
    MFMA(acc11, __builtin_bit_cast(short8, v3), *(const short8*)(b1p + 3 * 32));
    MFMA(acc00, __builtin_bit_cast(short8, v4), *(const short8*)(b0p + 4 * 32));
    MFMA(acc10, __builtin_bit_cast(short8, v4), *(const short8*)(b1p + 4 * 32));
    MFMA(acc01, __builtin_bit_cast(short8, v5), *(const short8*)(b0p + 5 * 32));
    MFMA(acc11, __builtin_bit_cast(short8, v5), *(const short8*)(b1p + 5 * 32));
    MFMA(acc00, __builtin_bit_cast(short8, v6), *(const short8*)(b0p + 6 * 32));
    MFMA(acc10, __builtin_bit_cast(short8, v6), *(const short8*)(b1p + 6 * 32));
    MFMA(acc01, __builtin_bit_cast(short8, v7), *(const short8*)(b0p + 7 * 32));
    MFMA(acc11, __builtin_bit_cast(short8, v7), *(const short8*)(b1p + 7 * 32));
  };

  xpart(0);
  for (int t = 0; t < T_STEPS; ++t) {
    // ---- wait until every block published h_t (slots[b] >= t) ----
    if (tid < 64) {
      const unsigned tu = (unsigned)t;
      for (;;) {
        unsigned v0 = __hip_atomic_load(&slots[lane],      __ATOMIC_RELAXED, __HIP_MEMORY_SCOPE_AGENT);
        unsigned v1 = __hip_atomic_load(&slots[lane + 64], __ATOMIC_RELAXED, __HIP_MEMORY_SCOPE_AGENT);
        if (__all((v0 >= tu) && (v1 >= tu))) break;
        __builtin_amdgcn_s_sleep(1);
      }
    }
    __syncthreads();            // h_t visible (uncached reads, L3 coherent)

    { // ---- h-part GEMM: pipelined uncached dwordx4 A-loads (4 batches of 8)
      const ushort* hb = hbf + (size_t)(t & 1) * (BATCH * HID)
                             + (size_t)m0 * HID + kgrp8;
      i32x4 p0, p1, p2, p3, p4, p5, p6, p7;
      i32x4 q0, q1, q2, q3, q4, q5, q6, q7;
      GLD(p0, hb, 0);    GLD(p1, hb, 64);   GLD(p2, hb, 128);  GLD(p3, hb, 192);
      GLD(p4, hb, 256);  GLD(p5, hb, 320);  GLD(p6, hb, 384);  GLD(p7, hb, 448);
      GLD(q0, hb, 512);  GLD(q1, hb, 576);  GLD(q2, hb, 640);  GLD(q3, hb, 704);
      GLD(q4, hb, 768);  GLD(q5, hb, 832);  GLD(q6, hb, 896);  GLD(q7, hb, 960);
      TIE(8, p0, p1, p2, p3, p4, p5, p6, p7);
      consume8(p0, p1, p2, p3, p4, p5, p6, p7, 0);
      GLD(p0, hb, 1024); GLD(p1, hb, 1088); GLD(p2, hb, 1152); GLD(p3, hb, 1216);
      GLD(p4, hb, 1280); GLD(p5, hb, 1344); GLD(p6, hb, 1408); GLD(p7, hb, 1472);
      TIE(8, q0, q1, q2, q3, q4, q5, q6, q7);
      consume8(q0, q1, q2, q3, q4, q5, q6, q7, 8);
      GLD(q0, hb, 1536); GLD(q1, hb, 1600); GLD(q2, hb, 1664); GLD(q3, hb, 1728);
      GLD(q4, hb, 1792); GLD(q5, hb, 1856); GLD(q6, hb, 1920); GLD(q7, hb, 1984);
      TIE(8, p0, p1, p2, p3, p4, p5, p6, p7);
      consume8(p0, p1, p2, p3, p4, p5, p6, p7, 16);
      TIE(0, q0, q1, q2, q3, q4, q5, q6, q7);
      consume8(q0, q1, q2, q3, q4, q5, q6, q7, 24);
    }

    { // store gate tiles [n][m] to LDS
      f32x4 g0 = acc00 + acc01, g1 = acc10 + acc11;
      int n0 = lane & 15;
      int mq = wave * 16 + (lane >> 4) * 4;
      *(f32x4*)&gates[n0][mq]      = g0;
      *(f32x4*)&gates[16 + n0][mq] = g1;
    }
    __syncthreads();

    if (tid < BATCH) {          // wave 0 only: elementwise cell, 1 batch row each
      const int m = tid;
      float h8[8], c8[8];
#pragma unroll
      for (int jj = 0; jj < 8; ++jj) {
        float fp = gates[jj][m]      + blds[jj];
        float ip = gates[8 + jj][m]  + blds[8 + jj];
        float gp = gates[16 + jj][m] + blds[16 + jj];
        float op = gates[24 + jj][m] + blds[24 + jj];
        float fs = 1.f / (1.f + __expf(-fp));
        float is = 1.f / (1.f + __expf(-ip));
        float os = 1.f / (1.f + __expf(-op));
        float gt = 1.f - 2.f / (__expf(2.f * gp) + 1.f);   // tanh, inf-safe
        float c  = fs * clds[jj][m] + is * gt;
        clds[jj][m] = c;
        float th = 1.f - 2.f / (__expf(2.f * c) + 1.f);
        h8[jj] = os * th;
        c8[jj] = c;
      }
      // publish h_{t+1}: two packed u64 agent-atomic stores (L3-coherent),
      // then drain own stores before releasing the slot
      unsigned long long hl = (unsigned long long)f2bf(h8[0])
                            | ((unsigned long long)f2bf(h8[1]) << 16)
                            | ((unsigned long long)f2bf(h8[2]) << 32)
                            | ((unsigned long long)f2bf(h8[3]) << 48);
      unsigned long long hh = (unsigned long long)f2bf(h8[4])
                            | ((unsigned long long)f2bf(h8[5]) << 16)
                            | ((unsigned long long)f2bf(h8[6]) << 32)
                            | ((unsigned long long)f2bf(h8[7]) << 48);
      unsigned long long* hp64 =
          (unsigned long long*)(hbf + (size_t)((t + 1) & 1) * (BATCH * HID)
                                    + (size_t)m * HID + jbase);
      __hip_atomic_store(hp64,     hl, __ATOMIC_RELAXED, __HIP_MEMORY_SCOPE_AGENT);
      __hip_atomic_store(hp64 + 1, hh, __ATOMIC_RELAXED, __HIP_MEMORY_SCOPE_AGENT);
      asm volatile("s_waitcnt vmcnt(0)" ::: "memory");
      if (tid == 0)
        __hip_atomic_store(&slots[bl], (unsigned)(t + 1),
                           __ATOMIC_RELAXED, __HIP_MEMORY_SCOPE_AGENT);
      // out stores: normal cached writes, off the critical path
      float* op0 = out + (size_t)t * (BATCH * HID) + (size_t)m * HID + jbase;
      *(float4*)op0       = make_float4(h8[0], h8[1], h8[2], h8[3]);
      *(float4*)(op0 + 4) = make_float4(h8[4], h8[5], h8[6], h8[7]);
      if (t == T_STEPS - 1) {
        float* hp = out + (size_t)T_STEPS * BATCH * HID + (size_t)m * HID + jbase;
        float* cp = hp + BATCH * HID;
        *(float4*)hp       = make_float4(h8[0], h8[1], h8[2], h8[3]);
        *(float4*)(hp + 4) = make_float4(h8[4], h8[5], h8[6], h8[7]);
        *(float4*)cp       = make_float4(c8[0], c8[1], c8[2], c8[3]);
        *(float4*)(cp + 4) = make_float4(c8[4], c8[5], c8[6], c8[7]);
      }
    }

    if (t < T_STEPS - 1) xpart(t + 1);   // waves 1-3 start immediately
  }
}

extern "C" void kernel_launch(void* const* d_in, const int* in_sizes, int n_in,
                              void* d_out, int out_size, void* d_ws, size_t ws_size,
                              hipStream_t stream) {
  const float* x   = (const float*)d_in[0];
  const float* Wf  = (const float*)d_in[1];
  const float* bfv = (const float*)d_in[2];
  const float* Wi  = (const float*)d_in[3];
  const float* biv = (const float*)d_in[4];
  const float* Wg  = (const float*)d_in[5];
  const float* bgv = (const float*)d_in[6];
  const float* Wo  = (const float*)d_in[7];
  const float* bov = (const float*)d_in[8];

  char* ws = (char*)d_ws;
  ushort*   Wpack = (ushort*)(ws + WS_WPACK);
  ushort*   Xbf   = (ushort*)(ws + WS_XBF);
  ushort*   hbf   = (ushort*)(ws + WS_HBF);
  float*    bpack = (float*)(ws + WS_BPK);
  unsigned* slots = (unsigned*)(ws + WS_SLOTS);
  float*    out   = (float*)d_out;

  prep_x<<<dim3((T_STEPS * BATCH * DIN) / 4 / 256), dim3(256), 0, stream>>>(
      x, Xbf, hbf, slots, bfv, biv, bgv, bov, bpack);
  prep_w<<<dim3(NBLK * NPB), dim3(256), 0, stream>>>(Wf, Wi, Wg, Wo, Wpack);

  const ushort* Wpc = Wpack;
  const ushort* Xbc = Xbf;
  const float*  bpc = bpack;
  void* args[] = {(void*)&Wpc, (void*)&Xbc, (void*)&hbf,
                  (void*)&bpc, (void*)&slots, (void*)&out};
  hipLaunchCooperativeKernel((const void*)lstm_persist, dim3(NBLK), dim3(256),
                             args, 0, stream);
}